// Round 1
// baseline (2088.441 us; speedup 1.0000x reference)
//
#include <hip/hip_runtime.h>
#include <stdint.h>
#include <stddef.h>

// Problem constants
constexpr int V = 32000, E = 256, H = 512, B = 64, T = 512;
constexpr int NTHR = 512;        // 8 waves
constexpr int NBLK = 64;         // 4 groups x 16 blocks
constexpr int BATG = 16;         // batches per group
constexpr int HPB = 32;          // hidden units per block (128 gate rows)

// LDS: Ps [8 waves][128 rows * 17 + pad]
constexpr int PSW = 128 * 17;                       // 2176 floats per wave
constexpr int OFF_PS   = 0;                         // 8*2176*4 = 69632
constexpr int OFF_BIAS = OFF_PS + 8 * PSW * 4;      // 69632
constexpr int OFF_LEN  = OFF_BIAS + 128 * 4;        // 70144
constexpr int LDS_BYTES = 84 * 1024;                // force 1 block/CU

// Output layout (flat fp32): output | hT | cT | mask
constexpr size_t OUT_HT   = (size_t)B * T * H;
constexpr size_t OUT_CT   = OUT_HT + (size_t)B * H;
constexpr size_t OUT_MASK = OUT_CT + (size_t)B * H;

typedef __attribute__((ext_vector_type(8))) short short8;   // 8 bf16
typedef __attribute__((ext_vector_type(4))) float f32x4;
typedef __attribute__((ext_vector_type(4))) unsigned int u32x4;

__device__ __forceinline__ unsigned short f2bf(float f) {   // RNE fp32->bf16
  uint32_t u = __builtin_bit_cast(uint32_t, f);
  return (unsigned short)((u + 0x7fffu + ((u >> 16) & 1u)) >> 16);
}
__device__ __forceinline__ short8 pack_bf8(float4 v0, float4 v1) {
  short8 r;
  r[0] = (short)f2bf(v0.x); r[1] = (short)f2bf(v0.y);
  r[2] = (short)f2bf(v0.z); r[3] = (short)f2bf(v0.w);
  r[4] = (short)f2bf(v1.x); r[5] = (short)f2bf(v1.y);
  r[6] = (short)f2bf(v1.z); r[7] = (short)f2bf(v1.w);
  return r;
}
__device__ __forceinline__ float sigmoidf_fast(float x) {
  return 1.f / (1.f + __expf(-x));
}
__device__ __forceinline__ float tanhf_fast(float x) {   // 1 - 2/(e^2x+1)
  return 1.f - 2.f / (__expf(2.f * x) + 1.f);            // inf-safe both tails
}
// MALL-coherent relaxed agent store (device scope; bypasses per-XCD L2)
__device__ __forceinline__ void st_word(uint32_t* p, uint32_t v) {
  __hip_atomic_store(p, v, __ATOMIC_RELAXED, __HIP_MEMORY_SCOPE_AGENT);
}
// 4x dwordx4 MALL-coherent loads: 16 fp32 = this wave's K=64 h-slice.
// offsets: s=0 -> {0,16}, s=1 (+32 dwords) -> {128,144}
__device__ __forceinline__ void ld_mall_k64(const uint32_t* p, u32x4& r0,
                                            u32x4& r1, u32x4& r2, u32x4& r3) {
  asm volatile(
      "global_load_dwordx4 %0, %4, off sc1\n\t"
      "global_load_dwordx4 %1, %4, off offset:16 sc1\n\t"
      "global_load_dwordx4 %2, %4, off offset:128 sc1\n\t"
      "global_load_dwordx4 %3, %4, off offset:144 sc1\n\t"
      "s_waitcnt vmcnt(0)"
      : "=&v"(r0), "=&v"(r1), "=&v"(r2), "=&v"(r3)
      : "v"(p)
      : "memory");
}
// pack 8 tagged-fp32 dwords -> short8 bf16 frag via v_cvt_pk_bf16_f32 (RNE)
__device__ __forceinline__ short8 cvt_frag(u32x4 lo, u32x4 hi) {
  uint32_t d0, d1, d2, d3;
  asm("v_cvt_pk_bf16_f32 %0, %1, %2" : "=v"(d0) : "v"(lo[0]), "v"(lo[1]));
  asm("v_cvt_pk_bf16_f32 %0, %1, %2" : "=v"(d1) : "v"(lo[2]), "v"(lo[3]));
  asm("v_cvt_pk_bf16_f32 %0, %1, %2" : "=v"(d2) : "v"(hi[0]), "v"(hi[1]));
  asm("v_cvt_pk_bf16_f32 %0, %1, %2" : "=v"(d3) : "v"(hi[2]), "v"(hi[3]));
  u32x4 d = {d0, d1, d2, d3};
  return __builtin_bit_cast(short8, d);
}

__global__ void __launch_bounds__(NTHR, 1)
lstm_mfma(const int* __restrict__ inputs, const int* __restrict__ lengths,
          const int* __restrict__ resets, const float* __restrict__ emb,
          const float* __restrict__ W_ih, const float* __restrict__ W_hh,
          const float* __restrict__ b_ih, const float* __restrict__ b_hh,
          float* __restrict__ out, uint32_t* __restrict__ hw) {
  extern __shared__ char lds[];
  float* Ps = (float*)(lds + OFF_PS);     // [wave][n(128)*17 + m(16)]
  float* Bias = (float*)(lds + OFF_BIAS);
  int* Lens = (int*)(lds + OFF_LEN);

  const int tid = threadIdx.x;
  const int blk = blockIdx.x;
  const int grp = blk & 3;        // batch group 0..3
  const int rq = blk >> 2;        // block rank in group 0..15
  const int khid = rq * HPB;      // hidden base (32 dims)
  const int b0 = grp * BATG;

  const int w = tid >> 6;         // wave 0..7
  const int L = tid & 63;
  const int lc = L & 15;          // A: batch m | B: gate row n within tile
  const int q = L >> 4;           // quad

  // ---- persistent W fragments (bf16), symmetric 8-wave K-split:
  // W_hh: K = 64*w + 32*s + 8*q, s=0..1  (2 frags x 8 tiles)
  // W_ih: K = 32*w + 8*q                  (1 frag  x 8 tiles)
  short8 wfh[2][8];
  short8 wfe[8];
  #pragma unroll
  for (int s = 0; s < 2; ++s) {
    #pragma unroll
    for (int tl = 0; tl < 8; ++tl) {
      const int n = 16 * tl + lc;
      const int grow = (n >> 5) * H + khid + (n & 31);
      const float* src = W_hh + (size_t)grow * H + 64 * w + 32 * s + 8 * q;
      wfh[s][tl] = pack_bf8(*(const float4*)src, *(const float4*)(src + 4));
    }
  }
  #pragma unroll
  for (int tl = 0; tl < 8; ++tl) {
    const int n = 16 * tl + lc;
    const int grow = (n >> 5) * H + khid + (n & 31);
    const float* src = W_ih + (size_t)grow * E + 32 * w + 8 * q;
    wfe[tl] = pack_bf8(*(const float4*)src, *(const float4*)(src + 4));
  }
  if (tid < 128) {
    const int grow = (tid >> 5) * H + khid + (tid & 31);
    Bias[tid] = b_ih[grow] + b_hh[grow];
  }
  if (tid < 16) Lens[tid] = lengths[b0 + tid];
  {  // mask output, fused: 64 blocks x 512 threads = B*T
    int i = blk * 512 + tid;
    int mb = i >> 9, mt = i & (T - 1);
    out[OUT_MASK + i] = (mt < lengths[mb]) ? 1.f : 0.f;
  }
  __syncthreads();

  const int jj = tid & 31;        // epilogue: hidden 0..31 (contig per wave)
  const int bb = tid >> 5;        // batch 0..15

  float carry_h = 0.f, carry_c = 0.f;

  for (int t = 0; t < T; ++t) {
    const uint32_t* hsrc = hw + (size_t)(t & 1) * (B * H);
    uint32_t* hdst = hw + (size_t)((t + 1) & 1) * (B * H);

    // ---- independent work first: resets + emb-side MFMA (all 8 waves)
    float rr = (float)resets[(b0 + bb) * T + t];
    const int tok = inputs[(b0 + lc) * T + t];
    const float* eb = emb + (size_t)tok * E + 32 * w + 8 * q;
    short8 ae = pack_bf8(*(const float4*)eb, *(const float4*)(eb + 4));
    f32x4 acc[8];
    const f32x4 zero4 = {0.f, 0.f, 0.f, 0.f};
    #pragma unroll
    for (int tl = 0; tl < 8; ++tl)
      acc[tl] = __builtin_amdgcn_mfma_f32_16x16x32_bf16(ae, wfe[tl], zero4, 0, 0, 0);

    if (t > 0) {
      // ---- self-validating h read: retry until all 16 dwords carry the
      // step tag.  tag(t) = 4 | ((t>>1)&3); stale data is at worst from
      // step t-3 (skew bound 2 via full-coverage-before-write), whose tag
      // differs; zero-initialized buffers never match (tag >= 4).
      const uint32_t expect = 4u | (((uint32_t)(t - 1) >> 1) & 3u);
      const uint32_t* p = hsrc + (size_t)(b0 + lc) * H + 64 * w + 8 * q;
      u32x4 r0, r1, r2, r3;
      for (;;) {
        ld_mall_k64(p, r0, r1, r2, r3);
        uint32_t o = (r0[0] | r0[1] | r0[2] | r0[3]) |
                     (r1[0] | r1[1] | r1[2] | r1[3]) |
                     (r2[0] | r2[1] | r2[2] | r2[3]) |
                     (r3[0] | r3[1] | r3[2] | r3[3]);
        uint32_t a = (r0[0] & r0[1] & r0[2] & r0[3]) &
                     (r1[0] & r1[1] & r1[2] & r1[3]) &
                     (r2[0] & r2[1] & r2[2] & r2[3]) &
                     (r3[0] & r3[1] & r3[2] & r3[3]);
        uint32_t bad = ((o ^ expect) | (a ^ expect)) & 7u;
        if (!__any((int)bad)) break;
      }
      short8 a0 = cvt_frag(r0, r1);   // K = 64w+8q   .. +8
      short8 a1 = cvt_frag(r2, r3);   // K = 64w+32+8q .. +8
      #pragma unroll
      for (int tl = 0; tl < 8; ++tl)
        acc[tl] = __builtin_amdgcn_mfma_f32_16x16x32_bf16(a0, wfh[0][tl], acc[tl], 0, 0, 0);
      #pragma unroll
      for (int tl = 0; tl < 8; ++tl)
        acc[tl] = __builtin_amdgcn_mfma_f32_16x16x32_bf16(a1, wfh[1][tl], acc[tl], 0, 0, 0);
    }

    // partials: D[m=4q+reg][n=16tl+lc] -> Ps[w*PSW + n*17 + m]
    #pragma unroll
    for (int tl = 0; tl < 8; ++tl)
      *(f32x4*)(Ps + w * PSW + (16 * tl + lc) * 17 + 4 * q) = acc[tl];
    __syncthreads();

    // ---- fused reduce + activations + state update (all 512 threads)
    float g4[4];
    #pragma unroll
    for (int gi = 0; gi < 4; ++gi) {
      const int n = gi * 32 + jj;
      float s = Bias[n];
      #pragma unroll
      for (int ww = 0; ww < 8; ++ww) s += Ps[ww * PSW + n * 17 + bb];
      g4[gi] = s;
    }
    __syncthreads();              // all Ps reads done -> safe to rewrite next t

    float ig = sigmoidf_fast(g4[0]);
    float fg = sigmoidf_fast(g4[1]);
    float gg = tanhf_fast(g4[2]);
    float og = sigmoidf_fast(g4[3]);
    float c_new = fg * carry_c + ig * gg;
    float h_new = og * tanhf_fast(c_new);
    bool live = (t < Lens[bb]);
    float h_next = live ? h_new : carry_h;   // carry regs are exact fp32
    float c_next = live ? c_new : carry_c;
    carry_h = h_next * (1.f - rr);
    carry_c = c_next * (1.f - rr);

    // tagged fp32 broadcast: one dword per thread, no ack, no flag
    if (t < T - 1) {
      const uint32_t wtag = 4u | (((uint32_t)t >> 1) & 3u);
      uint32_t bits = (__builtin_bit_cast(uint32_t, carry_h) & ~7u) | wtag;
      st_word(hdst + (size_t)(b0 + bb) * H + HPB * rq + jj, bits);
    }
    // HBM output store off the critical path
    out[((size_t)(b0 + bb) * T + t) * H + khid + jj] = h_next;
  }
  out[OUT_HT + (size_t)(b0 + bb) * H + khid + jj] = carry_h;
  out[OUT_CT + (size_t)(b0 + bb) * H + khid + jj] = carry_c;
}

extern "C" void kernel_launch(void* const* d_in, const int* in_sizes, int n_in,
                              void* d_out, int out_size, void* d_ws, size_t ws_size,
                              hipStream_t stream) {
  const int* inputs    = (const int*)d_in[0];
  const int* lengths   = (const int*)d_in[1];
  const int* resets    = (const int*)d_in[2];
  const float* emb     = (const float*)d_in[3];
  const float* W_ih    = (const float*)d_in[4];
  const float* W_hh    = (const float*)d_in[5];
  const float* b_ih    = (const float*)d_in[6];
  const float* b_hh    = (const float*)d_in[7];
  float* out = (float*)d_out;

  // ws layout: tagged-fp32 h ping-pong, 2 x B x H dwords = 256 KB
  uint32_t* hw = (uint32_t*)d_ws;

  hipFuncSetAttribute((const void*)lstm_mfma,
                      hipFuncAttributeMaxDynamicSharedMemorySize, LDS_BYTES);

  hipMemsetAsync(d_ws, 0, (size_t)2 * B * H * 4, stream);  // tags=0: never valid
  lstm_mfma<<<NBLK, NTHR, LDS_BYTES, stream>>>(
      inputs, lengths, resets, emb, W_ih, W_hh, b_ih, b_hh, out, hw);
}